// Round 5
// baseline (4048.841 us; speedup 1.0000x reference)
//
#include <hip/hip_runtime.h>

#define B_ 8
#define N_ 32768
#define S_ 1024
#define C_ 96
#define T_ 512            // threads per FPS block (8 waves, 2/SIMD, 1 block/CU)
#define PK 32             // float2 pairs per thread (64 points)

typedef float f2v __attribute__((ext_vector_type(2)));

// d_out layout (float32, concatenated):
//   [0, B*S*3)                      new_xyz  (B,S,3)
//   [B*S*3, B*S*3+B*C*S)            new_fea  (B,C,S)
//   [B*S*3+B*C*S, +B*S)             indices  (B,S) as float

__global__ __launch_bounds__(T_)
__attribute__((amdgpu_waves_per_eu(2, 2)))   // 2 waves/SIMD -> 256-VGPR budget:
                                             // 192 coord regs fit ARCH VGPRs, no AGPR copies
void fps_kernel(
    const float* __restrict__ xyz,   // (B, N, 3)
    float* __restrict__ out)
{
#pragma clang fp contract(off)
  const int b    = blockIdx.x;
  const int tid  = threadIdx.x;
  const int wv   = tid >> 6;        // wave id 0..7
  const int lane = tid & 63;
  const float* xb = xyz + (size_t)b * N_ * 3;

  float* out_xyz = out;
  float* out_idx = out + (size_t)B_*S_*3 + (size_t)B_*C_*S_;

  // Running min sq-dists, thread-private f2v slots at s_dist2[k*T_ + tid].
  // ds_read_b64/ds_write_b64, perfectly bank-balanced.
  __shared__ f2v   s_dist2[N_/2];   // 128 KiB
  __shared__ float s_v[2][8];       // per-wave partial max, parity double-buffered
  __shared__ int   s_i[2][8];

  // Coordinates as float2 pairs (global points 2k*T_+tid, (2k+1)*T_+tid).
  f2v X[PK], Y[PK], Z[PK];
  #pragma unroll
  for (int k = 0; k < PK; ++k) {
    const int g0 = (2*k)   * T_ + tid;
    const int g1 = (2*k+1) * T_ + tid;
    X[k] = (f2v){xb[g0*3+0], xb[g1*3+0]};
    Y[k] = (f2v){xb[g0*3+1], xb[g1*3+1]};
    Z[k] = (f2v){xb[g0*3+2], xb[g1*3+2]};
    s_dist2[k*T_ + tid] = (f2v){1e10f, 1e10f};
  }
  // Pin coords: asm-defined values are not rematerializable (no reload "spills").
  #pragma unroll
  for (int k = 0; k < PK; ++k) {
    asm volatile("" : "+v"(X[k]), "+v"(Y[k]), "+v"(Z[k]));
  }
  // No barrier: every thread touches only its own s_dist2 slots.

  int cur = 0;
  for (int s = 0; s < S_; ++s) {
    // cur is block-uniform: force scalar so coord broadcast is an SMEM load.
    const int cu = __builtin_amdgcn_readfirstlane(cur);
    const float cx = xb[cu*3+0];
    const float cy = xb[cu*3+1];
    const float cz = xb[cu*3+2];
    if (tid == 0) {
      out_idx[(size_t)b*S_ + s] = (float)cu;
      float* o = out_xyz + ((size_t)b*S_ + s)*3;
      o[0] = cx; o[1] = cy; o[2] = cz;
    }
    const f2v c2x = (f2v){cx, cx};
    const f2v c2y = (f2v){cy, cy};
    const f2v c2z = (f2v){cz, cz};

    // Update min-dists (packed fp32, exact IEEE order, no contraction);
    // per-thread argmax with first-index tie-break (ascending k, strict >).
    float bv = -1.0f;
    int   bj = 0;
    #pragma unroll
    for (int k = 0; k < PK; ++k) {
      const int o2 = k * T_ + tid;
      const f2v od = s_dist2[o2];
      const f2v dx = X[k] - c2x;
      const f2v dy = Y[k] - c2y;
      const f2v dz = Z[k] - c2z;
      const f2v d  = (dx*dx + dy*dy) + dz*dz;   // ((dx^2+dy^2)+dz^2), np order
      f2v nd;
      nd.x = fminf(od.x, d.x);
      nd.y = fminf(od.y, d.y);
      s_dist2[o2] = nd;
      if (nd.x > bv) { bv = nd.x; bj = 2*k;   }
      if (nd.y > bv) { bv = nd.y; bj = 2*k+1; }
    }
    int bg = (bj << 9) + tid;     // true global point index (T_ == 512)

    // In-wave argmax reduce (lane 0 ends with wave winner), smallest-index ties.
    #pragma unroll
    for (int off = 32; off > 0; off >>= 1) {
      const float ov = __shfl_down(bv, off);
      const int   og = __shfl_down(bg, off);
      if (ov > bv || (ov == bv && og < bg)) { bv = ov; bg = og; }
    }
    const int par = s & 1;
    if (lane == 0) { s_v[par][wv] = bv; s_i[par][wv] = bg; }
    __syncthreads();   // single barrier per step (parity buffers make it safe)

    // Every wave redundantly reduces the 8 partials -> block winner in all lanes.
    float v = s_v[par][lane & 7];
    int   g = s_i[par][lane & 7];
    #pragma unroll
    for (int m = 4; m > 0; m >>= 1) {
      const float ov = __shfl_xor(v, m);
      const int   og = __shfl_xor(g, m);
      if (ov > v || (ov == v && og < g)) { v = ov; g = og; }
    }
    cur = g;
  }
}

__global__ void gather_fea_kernel(
    const float* __restrict__ feat,   // (B, C, N)
    const float* __restrict__ idxf,   // (B, S) float indices (in d_out)
    float* __restrict__ out_fea)      // (B, C, S)
{
  const int t = blockIdx.x * blockDim.x + threadIdx.x;
  if (t >= B_ * C_ * S_) return;
  const int s  = t & (S_ - 1);
  const int bc = t >> 10;           // S_ == 1024
  const int c  = bc % C_;
  const int b  = bc / C_;
  const int idx = (int)idxf[(size_t)b * S_ + s];
  out_fea[t] = feat[((size_t)b * C_ + c) * (size_t)N_ + idx];
}

extern "C" void kernel_launch(void* const* d_in, const int* in_sizes, int n_in,
                              void* d_out, int out_size, void* d_ws, size_t ws_size,
                              hipStream_t stream) {
  const float* xyz  = (const float*)d_in[0];   // (B,N,3)
  const float* feat = (const float*)d_in[1];   // (B,C,N)
  float* out = (float*)d_out;

  float* out_fea = out + (size_t)B_ * S_ * 3;
  float* out_idx = out + (size_t)B_ * S_ * 3 + (size_t)B_ * C_ * S_;
  (void)d_ws; (void)ws_size; (void)in_sizes; (void)n_in; (void)out_size;

  fps_kernel<<<B_, T_, 0, stream>>>(xyz, out);

  const int total = B_ * C_ * S_;
  gather_fea_kernel<<<(total + 255) / 256, 256, 0, stream>>>(feat, out_idx, out_fea);
}

// Round 6
// 3529.818 us; speedup vs baseline: 1.1470x; 1.1470x over previous
//
#include <hip/hip_runtime.h>

#define B_ 8
#define N_ 32768
#define S_ 1024
#define C_ 96
#define M_ 8               // blocks per batch (cross-block sync via atomicMax key)
#define T_ 1024            // threads per block (16 waves)
#define CHUNK (N_ / M_)    // 4096 points per block
#define PPT (CHUNK / T_)   // 4 points per thread
#define PK (PPT / 2)       // 2 float2 pairs per thread

typedef float f2v __attribute__((ext_vector_type(2)));
typedef unsigned long long u64;
typedef unsigned int u32;

// Per-(batch,step) sync slot. key = (dist_bits << 32) | ~idx : dist >= 0 so
// float bits are unsigned-monotone; ~idx makes ties resolve to SMALLEST idx
// under max. cnt counts arrived blocks. Zeroed by hipMemsetAsync pre-launch.
struct Slot { u64 key; u32 cnt; u32 pad; };

// d_out layout (float32, concatenated):
//   [0, B*S*3)                      new_xyz  (B,S,3)
//   [B*S*3, B*S*3+B*C*S)            new_fea  (B,C,S)
//   [B*S*3+B*C*S, +B*S)             indices  (B,S) as float

__global__ __launch_bounds__(T_) void fps_kernel(
    const float* __restrict__ xyz,   // (B, N, 3)
    float* __restrict__ out,
    Slot* __restrict__ slots)        // (B_, S_) slots in d_ws
{
#pragma clang fp contract(off)
  const int blk  = blockIdx.x;
  const int b    = blk & 7;          // batch: blocks of a batch share XCD (heuristic)
  const int m    = blk >> 3;         // sub-block 0..M_-1
  const int tid  = threadIdx.x;
  const int wv   = tid >> 6;
  const int lane = tid & 63;
  const float* xb = xyz + (size_t)b * N_ * 3;
  const int base = m * CHUNK;        // this block's point range [base, base+CHUNK)

  float* out_xyz = out;
  float* out_idx = out + (size_t)B_*S_*3 + (size_t)B_*C_*S_;

  __shared__ float s_v[16];
  __shared__ int   s_i[16];
  __shared__ int   s_cur;

  // Coords AND running min-dists fully in registers (12 + 4 VGPRs).
  f2v X[PK], Y[PK], Z[PK], D[PK];
  #pragma unroll
  for (int k = 0; k < PK; ++k) {
    const int g0 = base + (2*k)   * T_ + tid;
    const int g1 = base + (2*k+1) * T_ + tid;
    X[k] = (f2v){xb[g0*3+0], xb[g1*3+0]};
    Y[k] = (f2v){xb[g0*3+1], xb[g1*3+1]};
    Z[k] = (f2v){xb[g0*3+2], xb[g1*3+2]};
    D[k] = (f2v){1e10f, 1e10f};
  }
  #pragma unroll
  for (int k = 0; k < PK; ++k) {
    asm volatile("" : "+v"(X[k]), "+v"(Y[k]), "+v"(Z[k]));  // keep live, no reloads
  }

  int cur = 0;
  for (int s = 0; s < S_; ++s) {
    const int cu = __builtin_amdgcn_readfirstlane(cur);
    const float cx = xb[cu*3+0];
    const float cy = xb[cu*3+1];
    const float cz = xb[cu*3+2];
    if (m == 0 && tid == 0) {
      out_idx[(size_t)b*S_ + s] = (float)cu;
      float* o = out_xyz + ((size_t)b*S_ + s)*3;
      o[0] = cx; o[1] = cy; o[2] = cz;
    }
    const f2v c2x = (f2v){cx, cx};
    const f2v c2y = (f2v){cy, cy};
    const f2v c2z = (f2v){cz, cz};

    // Exact IEEE ((dx^2+dy^2)+dz^2), no contraction; argmax w/ first-index ties.
    float bv = -1.0f;
    int   bj = 0;
    #pragma unroll
    for (int k = 0; k < PK; ++k) {
      const f2v dx = X[k] - c2x;
      const f2v dy = Y[k] - c2y;
      const f2v dz = Z[k] - c2z;
      const f2v d  = (dx*dx + dy*dy) + dz*dz;
      f2v nd;
      nd.x = fminf(D[k].x, d.x);
      nd.y = fminf(D[k].y, d.y);
      D[k] = nd;
      if (nd.x > bv) { bv = nd.x; bj = 2*k;   }
      if (nd.y > bv) { bv = nd.y; bj = 2*k+1; }
    }
    int bg = base + (bj << 10) + tid;   // global point index (T_ == 1024)

    // In-wave argmax reduce, smallest-index ties.
    #pragma unroll
    for (int off = 32; off > 0; off >>= 1) {
      const float ov = __shfl_down(bv, off);
      const int   og = __shfl_down(bg, off);
      if (ov > bv || (ov == bv && og < bg)) { bv = ov; bg = og; }
    }
    if (lane == 0) { s_v[wv] = bv; s_i[wv] = bg; }
    __syncthreads();

    // Wave 0: block reduce, cross-block combine via atomic key-max, spin, publish.
    if (wv == 0) {
      float v = s_v[lane & 15];
      int   g = s_i[lane & 15];
      #pragma unroll
      for (int mm = 8; mm > 0; mm >>= 1) {
        const float ov = __shfl_xor(v, mm);
        const int   og = __shfl_xor(g, mm);
        if (ov > v || (ov == v && og < g)) { v = ov; g = og; }
      }
      if (lane == 0) {
        Slot* sl = &slots[b * S_ + s];
        const u64 key = ((u64)__float_as_uint(v) << 32) | (u32)(~g);
        __hip_atomic_fetch_max(&sl->key, key, __ATOMIC_RELAXED, __HIP_MEMORY_SCOPE_AGENT);
        __hip_atomic_fetch_add(&sl->cnt, 1u, __ATOMIC_RELEASE, __HIP_MEMORY_SCOPE_AGENT);
        while (__hip_atomic_load(&sl->cnt, __ATOMIC_RELAXED, __HIP_MEMORY_SCOPE_AGENT) < (u32)M_) {
          __builtin_amdgcn_s_sleep(1);
        }
        (void)__hip_atomic_load(&sl->cnt, __ATOMIC_ACQUIRE, __HIP_MEMORY_SCOPE_AGENT);
        const u64 win = __hip_atomic_load(&sl->key, __ATOMIC_RELAXED, __HIP_MEMORY_SCOPE_AGENT);
        s_cur = (int)(~(u32)win);
      }
    }
    __syncthreads();
    cur = s_cur;
  }
}

__global__ void gather_fea_kernel(
    const float* __restrict__ feat,   // (B, C, N)
    const float* __restrict__ idxf,   // (B, S) float indices (in d_out)
    float* __restrict__ out_fea)      // (B, C, S)
{
  const int t = blockIdx.x * blockDim.x + threadIdx.x;
  if (t >= B_ * C_ * S_) return;
  const int s  = t & (S_ - 1);
  const int bc = t >> 10;           // S_ == 1024
  const int c  = bc % C_;
  const int b  = bc / C_;
  const int idx = (int)idxf[(size_t)b * S_ + s];
  out_fea[t] = feat[((size_t)b * C_ + c) * (size_t)N_ + idx];
}

extern "C" void kernel_launch(void* const* d_in, const int* in_sizes, int n_in,
                              void* d_out, int out_size, void* d_ws, size_t ws_size,
                              hipStream_t stream) {
  const float* xyz  = (const float*)d_in[0];   // (B,N,3)
  const float* feat = (const float*)d_in[1];   // (B,C,N)
  float* out = (float*)d_out;

  float* out_fea = out + (size_t)B_ * S_ * 3;
  float* out_idx = out + (size_t)B_ * S_ * 3 + (size_t)B_ * C_ * S_;
  Slot* slots = (Slot*)d_ws;
  (void)ws_size; (void)in_sizes; (void)n_in; (void)out_size;

  // Zero the sync slots (d_ws is re-poisoned 0xAA before every launch).
  hipMemsetAsync(d_ws, 0, (size_t)B_ * S_ * sizeof(Slot), stream);

  fps_kernel<<<B_ * M_, T_, 0, stream>>>(xyz, out, slots);

  const int total = B_ * C_ * S_;
  gather_fea_kernel<<<(total + 255) / 256, 256, 0, stream>>>(feat, out_idx, out_fea);
}

// Round 7
// 2904.780 us; speedup vs baseline: 1.3939x; 1.2152x over previous
//
#include <hip/hip_runtime.h>

#define B_ 8
#define N_ 32768
#define S_ 1024
#define C_ 96
#define M_ 32              // blocks per batch (flat all-to-all key exchange)
#define T_ 64              // ONE wave per block: no __syncthreads, no LDS reduce
#define PPB (N_ / M_)      // 1024 points per block
#define PPT (PPB / T_)     // 16 points per thread
#define PK (PPT / 2)       // 8 float2 pairs per thread

typedef float f2v __attribute__((ext_vector_type(2)));
typedef unsigned long long u64;
typedef unsigned int u32;

// Key = (float_bits(dist) << 32) | ~idx. dist >= 0 so bits are unsigned-
// monotone in dist; ~idx makes u64-max prefer the SMALLEST index on ties.
// The key IS the payload -> relaxed atomics, no fences needed. One fresh
// slot row of M_ keys per (batch, step): no ABA, fast blocks can run ahead.

// d_out layout (float32, concatenated):
//   [0, B*S*3)                      new_xyz  (B,S,3)
//   [B*S*3, B*S*3+B*C*S)            new_fea  (B,C,S)  <- doubles as slot scratch
//   [B*S*3+B*C*S, +B*S)             indices  (B,S) as float

__global__ __launch_bounds__(T_)
__attribute__((amdgpu_waves_per_eu(1, 2)))   // 256-VGPR budget: coords+dists in regs
void fps_kernel(
    const float* __restrict__ xyz,   // (B, N, 3)
    float* __restrict__ out,
    u64* __restrict__ parts)         // (B_*S_, M_) key slots, pre-zeroed
{
#pragma clang fp contract(off)
  const int blk  = blockIdx.x;
  const int b    = blk & 7;          // batch (== XCD heuristic: batch-local L2)
  const int m    = blk >> 3;         // sub-block 0..M_-1
  const int lane = threadIdx.x;      // one wave
  const float* xb = xyz + (size_t)b * N_ * 3;
  const int base = m * PPB;

  float* out_xyz = out;
  float* out_idx = out + (size_t)B_*S_*3 + (size_t)B_*C_*S_;

  // Coords AND running min-dists fully in registers (48 + 16 VGPRs).
  f2v X[PK], Y[PK], Z[PK], D[PK];
  #pragma unroll
  for (int k = 0; k < PK; ++k) {
    const int g0 = base + (2*k)   * T_ + lane;
    const int g1 = base + (2*k+1) * T_ + lane;
    X[k] = (f2v){xb[g0*3+0], xb[g1*3+0]};
    Y[k] = (f2v){xb[g0*3+1], xb[g1*3+1]};
    Z[k] = (f2v){xb[g0*3+2], xb[g1*3+2]};
    D[k] = (f2v){1e10f, 1e10f};
  }
  #pragma unroll
  for (int k = 0; k < PK; ++k) {
    asm volatile("" : "+v"(X[k]), "+v"(Y[k]), "+v"(Z[k]));  // not rematerializable
  }

  int cur = 0;
  for (int s = 0; s < S_; ++s) {
    const int cu = __builtin_amdgcn_readfirstlane(cur);   // uniform -> scalar loads
    const float cx = xb[cu*3+0];
    const float cy = xb[cu*3+1];
    const float cz = xb[cu*3+2];
    if (m == 0 && lane == 0) {
      out_idx[(size_t)b*S_ + s] = (float)cu;
      float* o = out_xyz + ((size_t)b*S_ + s)*3;
      o[0] = cx; o[1] = cy; o[2] = cz;
    }
    const f2v c2x = (f2v){cx, cx};
    const f2v c2y = (f2v){cy, cy};
    const f2v c2z = (f2v){cz, cz};

    // Exact IEEE ((dx^2+dy^2)+dz^2), no contraction; per-thread argmax with
    // first-index tie-break (ascending j, strict >; idx(j0) < idx(j1) in pair).
    float bv = -1.0f;
    int   bj = 0;
    #pragma unroll
    for (int k = 0; k < PK; ++k) {
      const f2v dx = X[k] - c2x;
      const f2v dy = Y[k] - c2y;
      const f2v dz = Z[k] - c2z;
      const f2v d  = (dx*dx + dy*dy) + dz*dz;
      f2v nd;
      nd.x = fminf(D[k].x, d.x);
      nd.y = fminf(D[k].y, d.y);
      D[k] = nd;
      if (nd.x > bv) { bv = nd.x; bj = 2*k;   }
      if (nd.y > bv) { bv = nd.y; bj = 2*k+1; }
    }
    const int bg = base + (bj << 6) + lane;    // global point index (T_ == 64)

    // Pack and butterfly-max across the wave: all lanes end with block key.
    u64 key = ((u64)__float_as_uint(bv) << 32) | (u32)(~bg);
    #pragma unroll
    for (int off = 32; off > 0; off >>= 1) {
      const u64 ok = __shfl_xor(key, off);
      if (ok > key) key = ok;
    }

    // ONE-round-trip sync: publish partial, poll all 32 partials, combine locally.
    u64* row = parts + ((size_t)(b * S_ + s) << 5);
    if (lane == 0) {
      __hip_atomic_store(&row[m], key, __ATOMIC_RELAXED, __HIP_MEMORY_SCOPE_AGENT);
    }
    u64 k;
    do {
      k = __hip_atomic_load(&row[lane & 31], __ATOMIC_RELAXED, __HIP_MEMORY_SCOPE_AGENT);
    } while (__ballot(k != 0) != ~0ull);       // key is never 0 (~idx != 0)
    #pragma unroll
    for (int off = 32; off > 0; off >>= 1) {
      const u64 ok = __shfl_xor(k, off);
      if (ok > k) k = ok;
    }
    cur = (int)(u32)(~(u32)k);                 // decode winner index
  }
}

__global__ void gather_fea_kernel(
    const float* __restrict__ feat,   // (B, C, N)
    const float* __restrict__ idxf,   // (B, S) float indices (in d_out)
    float* __restrict__ out_fea)      // (B, C, S)
{
  const int t = blockIdx.x * blockDim.x + threadIdx.x;
  if (t >= B_ * C_ * S_) return;
  const int s  = t & (S_ - 1);
  const int bc = t >> 10;           // S_ == 1024
  const int c  = bc % C_;
  const int b  = bc / C_;
  const int idx = (int)idxf[(size_t)b * S_ + s];
  out_fea[t] = feat[((size_t)b * C_ + c) * (size_t)N_ + idx];
}

extern "C" void kernel_launch(void* const* d_in, const int* in_sizes, int n_in,
                              void* d_out, int out_size, void* d_ws, size_t ws_size,
                              hipStream_t stream) {
  const float* xyz  = (const float*)d_in[0];   // (B,N,3)
  const float* feat = (const float*)d_in[1];   // (B,C,N)
  float* out = (float*)d_out;

  float* out_fea = out + (size_t)B_ * S_ * 3;
  float* out_idx = out + (size_t)B_ * S_ * 3 + (size_t)B_ * C_ * S_;
  (void)d_ws; (void)ws_size; (void)in_sizes; (void)n_in; (void)out_size;

  // Slot scratch lives in the out_fea region (3 MB >= 2 MB needed); it is
  // fully overwritten by gather_fea_kernel afterwards. Zero it (poisoned 0xAA).
  u64* parts = (u64*)out_fea;
  hipMemsetAsync(parts, 0, (size_t)B_ * S_ * M_ * sizeof(u64), stream);

  fps_kernel<<<B_ * M_, T_, 0, stream>>>(xyz, out, parts);

  const int total = B_ * C_ * S_;
  gather_fea_kernel<<<(total + 255) / 256, 256, 0, stream>>>(feat, out_idx, out_fea);
}